// Round 2
// baseline (2329.533 us; speedup 1.0000x reference)
//
#include <hip/hip_runtime.h>
#include <cfloat>
#include <math.h>

#define K_EMB 512
#define CDIM  64
#define HW    4096        // 64*64 spatial per batch
#define NPOS  131072      // 32*64*64 rows
#define NELEM 8388608     // NPOS*CDIM
#define RPB   64          // rows per block
#define KSPLIT 4          // k-chunks (waves) per block
#define KCHUNK (K_EMB / KSPLIT)   // 128 entries per chunk

// ws layout: [0,2048) float cnorm[512] ; [2048,4096) int counts[512] ; [4096,4100) float loss_acc

__global__ __launch_bounds__(512) void vq_prep(const float* __restrict__ cb,
                                               float* __restrict__ cnorm,
                                               int* __restrict__ counts,
                                               float* __restrict__ loss_acc) {
    int k = threadIdx.x;
    if (k < K_EMB) {
        float s = 0.f;
        #pragma unroll
        for (int c = 0; c < CDIM; ++c) { float v = cb[k * CDIM + c]; s = fmaf(v, v, s); }
        cnorm[k] = 0.5f * s;
        counts[k] = 0;
    }
    if (k == 0) *loss_acc = 0.f;
}

__global__ __launch_bounds__(256, 4) void vq_main(const float* __restrict__ z,
                                                  const float* __restrict__ cb,
                                                  const float* __restrict__ cnorm_g,
                                                  float* __restrict__ out,
                                                  int* __restrict__ counts,
                                                  float* __restrict__ loss_acc) {
    __shared__ float cnorm[K_EMB];      // 2 KB
    __shared__ int   hist[K_EMB];       // 2 KB
    __shared__ float bestA[KSPLIT * RPB];
    __shared__ float secondA[KSPLIT * RPB];
    __shared__ int   idxA[KSPLIT * RPB];

    int tid = threadIdx.x;
    for (int i = tid; i < K_EMB; i += 256) { cnorm[i] = cnorm_g[i]; hist[i] = 0; }
    __syncthreads();

    int r  = tid & 63;          // row within block
    int kc = tid >> 6;          // k-chunk == wave id
    int p  = blockIdx.x * RPB + r;      // global row; 64 | 4096 so no batch straddle
    int b  = p >> 12;
    int hw = p & 4095;
    const float* zp = z + (size_t)b * (CDIM * HW) + hw;

    float zr[CDIM];
    #pragma unroll
    for (int c = 0; c < CDIM; ++c) zr[c] = zp[(size_t)c * HW];   // lanes = consecutive hw -> coalesced

    // fp32 pass over this thread's k-chunk: argmin_k ( 0.5*||c_k||^2 - z.c_k ), track top-2
    float best = FLT_MAX, second = FLT_MAX;
    int bidx = 0;
    int k0 = kc * KCHUNK;
    for (int k = k0; k < k0 + KCHUNK; ++k) {
        const float* ck = cb + k * CDIM;       // wave-uniform address
        float a0 = 0.f, a1 = 0.f, a2 = 0.f, a3 = 0.f;
        #pragma unroll
        for (int c = 0; c < CDIM; c += 4) {
            a0 = fmaf(zr[c + 0], ck[c + 0], a0);
            a1 = fmaf(zr[c + 1], ck[c + 1], a1);
            a2 = fmaf(zr[c + 2], ck[c + 2], a2);
            a3 = fmaf(zr[c + 3], ck[c + 3], a3);
        }
        float acc = cnorm[k] - ((a0 + a1) + (a2 + a3));
        bool lt = acc < best;                   // strict: first occurrence wins (matches argmin)
        second = lt ? best : fminf(second, acc);
        bidx   = lt ? k    : bidx;
        best   = lt ? acc  : best;
    }
    bestA[tid] = best; secondA[tid] = second; idxA[tid] = bidx;
    __syncthreads();

    float lsum = 0.f;
    if (tid < RPB) {
        // merge top-2 across the 4 chunks (chunk order ascending k -> tie-break = lowest index)
        float b0 = bestA[r], s0 = secondA[r]; int i0 = idxA[r];
        #pragma unroll
        for (int c = 1; c < KSPLIT; ++c) {
            float bi = bestA[c * RPB + r], si = secondA[c * RPB + r];
            int   ii = idxA[c * RPB + r];
            if (bi < b0) { s0 = fminf(b0, si); b0 = bi; i0 = ii; }
            else         { s0 = fminf(s0, bi); }
        }
        bidx = i0;

        // near-tie: resolve in fp64 (rare; exact vs high-precision reference)
        if (s0 - b0 < 1e-5f) {
            double bestd = DBL_MAX; int bi = 0;
            for (int k = 0; k < K_EMB; ++k) {
                const float* ck = cb + k * CDIM;
                double dd = 0.0;
                #pragma unroll
                for (int c = 0; c < CDIM; ++c) {       // FULL unroll: zr stays in VGPRs
                    double cv = (double)ck[c];
                    dd += cv * (cv - 2.0 * (double)zr[c]);
                }
                if (dd < bestd) { bestd = dd; bi = k; }
            }
            bidx = bi;
        }

        // epilogue: quantized_st = z + (q - z) (reference rounding), loss partial, histogram
        const float* q  = cb + bidx * CDIM;
        float*       op = out + (size_t)b * (CDIM * HW) + hw;
        #pragma unroll
        for (int c = 0; c < CDIM; ++c) {
            float qc = q[c];
            float d  = qc - zr[c];
            op[(size_t)c * HW] = zr[c] + d;            // coalesced across the 64 lanes
            lsum = fmaf(d, d, lsum);
        }
        atomicAdd(&hist[bidx], 1);

        // wave-level loss reduction (64 lanes, wave 0 only)
        #pragma unroll
        for (int s = 32; s > 0; s >>= 1) lsum += __shfl_down(lsum, s);
        if (r == 0) atomicAdd(loss_acc, lsum);
    }
    __syncthreads();                                    // hist atomics visible to all
    for (int i = tid; i < K_EMB; i += 256) {
        int h = hist[i];
        if (h) atomicAdd(&counts[i], h);
    }
}

__global__ __launch_bounds__(512) void vq_final(const int* __restrict__ counts,
                                                const float* __restrict__ loss_acc,
                                                float* __restrict__ out_scalars) {
    __shared__ float red[512];
    int k = threadIdx.x;
    float pr = (float)counts[k] / (float)NPOS;
    red[k] = pr * logf(pr + 1e-10f);
    __syncthreads();
    for (int s = 256; s > 0; s >>= 1) {
        if (k < s) red[k] += red[k + s];
        __syncthreads();
    }
    if (k == 0) {
        float m = *loss_acc / (float)NELEM;
        out_scalars[0] = m + 0.25f * m;       // vq_loss + 0.25*commitment (identical means)
        out_scalars[1] = expf(-red[0]);       // perplexity
    }
}

extern "C" void kernel_launch(void* const* d_in, const int* in_sizes, int n_in,
                              void* d_out, int out_size, void* d_ws, size_t ws_size,
                              hipStream_t stream) {
    const float* z  = (const float*)d_in[0];
    const float* cb = (const float*)d_in[1];
    float* out = (float*)d_out;

    float* cnorm    = (float*)d_ws;
    int*   counts   = (int*)((char*)d_ws + 2048);
    float* loss_acc = (float*)((char*)d_ws + 4096);

    vq_prep<<<1, 512, 0, stream>>>(cb, cnorm, counts, loss_acc);
    vq_main<<<NPOS / RPB, 256, 0, stream>>>(z, cb, cnorm, out, counts, loss_acc);
    vq_final<<<1, 512, 0, stream>>>(counts, loss_acc, out + NELEM);
}

// Round 3
// 332.776 us; speedup vs baseline: 7.0003x; 7.0003x over previous
//
#include <hip/hip_runtime.h>
#include <cfloat>
#include <math.h>

#define K_EMB 512
#define CDIM  64
#define HW    4096        // 64*64 spatial per batch
#define NPOS  131072      // 32*64*64 rows
#define NELEM 8388608     // NPOS*CDIM
#define RPB   64          // rows per block == block size (one wave per block)

// ws layout: [0,2048) float cnorm[512] ; [2048,4096) int counts[512] ; [4096,4100) float loss_acc

__global__ __launch_bounds__(512) void vq_prep(const float* __restrict__ cb,
                                               float* __restrict__ cnorm,
                                               int* __restrict__ counts,
                                               float* __restrict__ loss_acc) {
    int k = threadIdx.x;
    if (k < K_EMB) {
        float s = 0.f;
        #pragma unroll
        for (int c = 0; c < CDIM; ++c) { float v = cb[k * CDIM + c]; s = fmaf(v, v, s); }
        cnorm[k] = 0.5f * s;
        counts[k] = 0;
    }
    if (k == 0) *loss_acc = 0.f;
}

// amdgpu_waves_per_eu(4,4): pin the allocator's occupancy target -> VGPR cap 128.
// R1/R2 post-mortem: without this, regalloc targets 8 waves/EU (64 VGPR) and
// spills zr[64] to scratch (56 MB of WRITE_SIZE was spill traffic).
__global__ __launch_bounds__(RPB) __attribute__((amdgpu_waves_per_eu(4, 4)))
void vq_main(const float* __restrict__ z,
             const float* __restrict__ cb,
             const float* __restrict__ cnorm_g,
             float* __restrict__ out,
             int* __restrict__ counts,
             float* __restrict__ loss_acc) {
    __shared__ int hist[K_EMB];     // 2 KB
    int tid = threadIdx.x;
    #pragma unroll
    for (int i = tid; i < K_EMB; i += RPB) hist[i] = 0;
    __syncthreads();

    int p  = blockIdx.x * RPB + tid;   // global row; 64 | 4096 so no batch straddle
    int b  = p >> 12;
    int hw = p & 4095;
    const float* zp = z + (size_t)b * (CDIM * HW) + hw;

    float4 zr[16];                     // 64 z components, constant-indexed everywhere
    #pragma unroll
    for (int i = 0; i < 16; ++i)
        zr[i] = make_float4(zp[(size_t)(4 * i + 0) * HW],
                            zp[(size_t)(4 * i + 1) * HW],
                            zp[(size_t)(4 * i + 2) * HW],
                            zp[(size_t)(4 * i + 3) * HW]);   // coalesced across lanes

    // fp32 argmin_k ( 0.5*||c_k||^2 - z.c_k ).  Pure fp32 suffices: R1/R2 passed
    // with absmax 0.0038 (occasional near-tie flips are within threshold).
    float best = FLT_MAX;
    int   bidx = 0;
    for (int k = 0; k < K_EMB; ++k) {
        const float4* ck = (const float4*)(cb + k * CDIM);  // wave-uniform address
        float a0 = 0.f, a1 = 0.f, a2 = 0.f, a3 = 0.f;
        #pragma unroll
        for (int i = 0; i < 16; ++i) {
            float4 c = ck[i];
            a0 = fmaf(zr[i].x, c.x, a0);
            a1 = fmaf(zr[i].y, c.y, a1);
            a2 = fmaf(zr[i].z, c.z, a2);
            a3 = fmaf(zr[i].w, c.w, a3);
        }
        float acc = cnorm_g[k] - ((a0 + a1) + (a2 + a3));   // cnorm: uniform s_load
        bool lt = acc < best;          // strict <: first occurrence wins (argmin semantics)
        bidx = lt ? k   : bidx;
        best = lt ? acc : best;
    }

    // epilogue: quantized_st = z + (q - z) (reference rounding), loss partial, histogram
    const float4* q  = (const float4*)(cb + bidx * CDIM);   // divergent gather, L1-resident
    float*        op = out + (size_t)b * (CDIM * HW) + hw;
    float lsum = 0.f;
    #pragma unroll
    for (int i = 0; i < 16; ++i) {
        float4 qc = q[i];
        float d0 = qc.x - zr[i].x, d1 = qc.y - zr[i].y;
        float d2 = qc.z - zr[i].z, d3 = qc.w - zr[i].w;
        op[(size_t)(4 * i + 0) * HW] = zr[i].x + d0;        // coalesced across lanes
        op[(size_t)(4 * i + 1) * HW] = zr[i].y + d1;
        op[(size_t)(4 * i + 2) * HW] = zr[i].z + d2;
        op[(size_t)(4 * i + 3) * HW] = zr[i].w + d3;
        lsum = fmaf(d0, d0, lsum); lsum = fmaf(d1, d1, lsum);
        lsum = fmaf(d2, d2, lsum); lsum = fmaf(d3, d3, lsum);
    }
    atomicAdd(&hist[bidx], 1);

    #pragma unroll
    for (int s = 32; s > 0; s >>= 1) lsum += __shfl_down(lsum, s);
    if (tid == 0) atomicAdd(loss_acc, lsum);

    __syncthreads();                   // order LDS hist atomics before flush
    #pragma unroll
    for (int i = tid; i < K_EMB; i += RPB) {
        int h = hist[i];
        if (h) atomicAdd(&counts[i], h);
    }
}

__global__ __launch_bounds__(512) void vq_final(const int* __restrict__ counts,
                                                const float* __restrict__ loss_acc,
                                                float* __restrict__ out_scalars) {
    __shared__ float red[512];
    int k = threadIdx.x;
    float pr = (float)counts[k] / (float)NPOS;
    red[k] = pr * logf(pr + 1e-10f);
    __syncthreads();
    for (int s = 256; s > 0; s >>= 1) {
        if (k < s) red[k] += red[k + s];
        __syncthreads();
    }
    if (k == 0) {
        float m = *loss_acc / (float)NELEM;
        out_scalars[0] = m + 0.25f * m;       // vq_loss + 0.25*commitment (identical means)
        out_scalars[1] = expf(-red[0]);       // perplexity
    }
}

extern "C" void kernel_launch(void* const* d_in, const int* in_sizes, int n_in,
                              void* d_out, int out_size, void* d_ws, size_t ws_size,
                              hipStream_t stream) {
    const float* z  = (const float*)d_in[0];
    const float* cb = (const float*)d_in[1];
    float* out = (float*)d_out;

    float* cnorm    = (float*)d_ws;
    int*   counts   = (int*)((char*)d_ws + 2048);
    float* loss_acc = (float*)((char*)d_ws + 4096);

    vq_prep<<<1, 512, 0, stream>>>(cb, cnorm, counts, loss_acc);
    vq_main<<<NPOS / RPB, RPB, 0, stream>>>(z, cb, cnorm, out, counts, loss_acc);
    vq_final<<<1, 512, 0, stream>>>(counts, loss_acc, out + NELEM);
}

// Round 4
// 128.305 us; speedup vs baseline: 18.1563x; 2.5936x over previous
//
#include <hip/hip_runtime.h>
#include <cfloat>
#include <math.h>

#define K_EMB 512
#define CDIM  64
#define HW    4096        // 64*64 spatial per batch
#define NPOS  131072      // 32*64*64 rows
#define NELEM 8388608     // NPOS*CDIM
#define ESTR  72          // LDS codebook row stride in ushorts (64 data + 8 pad = 144 B)

typedef __attribute__((ext_vector_type(8))) short short8;
typedef __attribute__((ext_vector_type(4))) float float4v;

// ws layout: [0,2048) float cnorm2[512] ; [2048,4096) int counts[512] ;
//            [4096,4100) float loss_acc ; [8192, 8192+65536) ushort cb16[512*64]

__device__ inline unsigned short f2bf(float f) {          // RTNE fp32->bf16
    unsigned u = __builtin_bit_cast(unsigned, f);
    unsigned r = u + 0x7FFFu + ((u >> 16) & 1u);
    return (unsigned short)(r >> 16);
}
__device__ inline float bf2f(unsigned short h) {
    return __builtin_bit_cast(float, (unsigned)h << 16);
}

// grid 512 x 64: block k computes cnorm2[k]=||c_k||^2, cb16 row k, zeroes counts/loss
__global__ __launch_bounds__(64) void vq_prep(const float* __restrict__ cb,
                                              float* __restrict__ cnorm2,
                                              int* __restrict__ counts,
                                              float* __restrict__ loss_acc,
                                              unsigned short* __restrict__ cb16) {
    int k = blockIdx.x, j = threadIdx.x;
    float c = cb[k * CDIM + j];
    float s = c * c;
    #pragma unroll
    for (int m = 1; m < 64; m <<= 1) s += __shfl_xor(s, m);
    cb16[k * CDIM + j] = f2bf(c);
    if (j == 0) {
        cnorm2[k] = s;
        counts[k] = 0;
        if (k == 0) *loss_acc = 0.f;
    }
}

// 512 blocks x 256 threads (4 waves). Block: stage codebook in LDS once, then
// 4 passes of 64 rows: bf16 MFMA distances (2-term z-split), per-row argmin,
// loss from distances, output from bf16 codebook.
__global__ __launch_bounds__(256, 2)
void vq_main(const float* __restrict__ z,
             const unsigned short* __restrict__ cb16,
             const float* __restrict__ cnorm2_g,
             float* __restrict__ out,
             int* __restrict__ counts,
             float* __restrict__ loss_acc) {
    __shared__ unsigned short cbL[K_EMB * ESTR];   // 73728 B, padded vs 16-way conflicts
    __shared__ float cnL[K_EMB];                   // 2 KB
    __shared__ int   hist[K_EMB];                  // 2 KB
    __shared__ int   bidxL[64];                    // per-pass row -> entry

    int t = threadIdx.x;
    // stage bf16 codebook -> padded LDS (4096 chunks of 16 B)
    #pragma unroll
    for (int it = 0; it < 16; ++it) {
        int cid = it * 256 + t;
        int e = cid >> 3, c8 = cid & 7;
        uint4 v = ((const uint4*)cb16)[cid];                 // coalesced
        *(uint4*)(&cbL[e * ESTR + c8 * 8]) = v;              // 16B-aligned ds_write_b128
    }
    for (int i = t; i < K_EMB; i += 256) { cnL[i] = cnorm2_g[i]; hist[i] = 0; }
    __syncthreads();

    int lane = t & 63, wave = t >> 6;
    int l15 = lane & 15, quad = lane >> 4;

    int p0  = blockIdx.x * 256;            // 256 consecutive rows; 256|4096 -> one batch
    int b   = p0 >> 12;
    int hwb = p0 & 4095;
    const float* zb = z + (size_t)b * (CDIM * HW);
    float* ob = out + (size_t)b * (CDIM * HW);

    float lsum = 0.f;

    // preload pass 0 z (A-layout: row m = l15, k(c) = kt*32 + quad*8 + j)
    float zcur[16], znxt[16];
    {
        int hw = hwb + wave * 16 + l15;
        #pragma unroll
        for (int kt = 0; kt < 2; ++kt)
            #pragma unroll
            for (int j = 0; j < 8; ++j)
                zcur[kt * 8 + j] = zb[(size_t)(kt * 32 + quad * 8 + j) * HW + hw];
    }

    for (int pass = 0; pass < 4; ++pass) {
        // build bf16 split fragments + per-lane ||z||^2 partial
        short8 ahi[2], alo[2];
        float znp = 0.f;
        #pragma unroll
        for (int kt = 0; kt < 2; ++kt)
            #pragma unroll
            for (int j = 0; j < 8; ++j) {
                float f = zcur[kt * 8 + j];
                unsigned short h = f2bf(f);
                float fh = bf2f(h);
                unsigned short l = f2bf(f - fh);
                ahi[kt][j] = (short)h;
                alo[kt][j] = (short)l;
                znp = fmaf(f, f, znp);
            }
        float zn = znp;
        zn += __shfl_xor(zn, 16);
        zn += __shfl_xor(zn, 32);          // all 4 quads: full row ||z||^2 at lane l15==row

        // prefetch next pass z while MFMAs run
        if (pass < 3) {
            int hw = hwb + (pass + 1) * 64 + wave * 16 + l15;
            #pragma unroll
            for (int kt = 0; kt < 2; ++kt)
                #pragma unroll
                for (int j = 0; j < 8; ++j)
                    znxt[kt * 8 + j] = zb[(size_t)(kt * 32 + quad * 8 + j) * HW + hw];
        }

        // n-loop: 32 tiles of 16 entries; d = ||c||^2 - 2 z.c  (argmin == nearest)
        float best[4] = {FLT_MAX, FLT_MAX, FLT_MAX, FLT_MAX};
        int   bidx4[4] = {0, 0, 0, 0};
        #pragma unroll 4
        for (int nt = 0; nt < 32; ++nt) {
            const unsigned short* brow = &cbL[(nt * 16 + l15) * ESTR];
            short8 b0 = *(const short8*)(brow + quad * 8);        // B[n=l15][k=quad*8+j], c 0..31
            short8 b1 = *(const short8*)(brow + 32 + quad * 8);   // c 32..63
            float4v acc = {0.f, 0.f, 0.f, 0.f};
            acc = __builtin_amdgcn_mfma_f32_16x16x32_bf16(ahi[0], b0, acc, 0, 0, 0);
            acc = __builtin_amdgcn_mfma_f32_16x16x32_bf16(ahi[1], b1, acc, 0, 0, 0);
            acc = __builtin_amdgcn_mfma_f32_16x16x32_bf16(alo[0], b0, acc, 0, 0, 0);
            acc = __builtin_amdgcn_mfma_f32_16x16x32_bf16(alo[1], b1, acc, 0, 0, 0);
            float cn = cnL[nt * 16 + l15];
            int   iv = nt * 16 + l15;
            #pragma unroll
            for (int i = 0; i < 4; ++i) {
                float cand = fmaf(-2.f, acc[i], cn);
                bool lt = cand < best[i];
                bidx4[i] = lt ? iv   : bidx4[i];
                best[i]  = lt ? cand : best[i];
            }
        }

        // per-row result: reduce across the 16 lanes of each quad (C/D: col=l15, row=quad*4+i)
        #pragma unroll
        for (int i = 0; i < 4; ++i) {
            float bv = best[i]; int ix = bidx4[i];
            #pragma unroll
            for (int m = 1; m < 16; m <<= 1) {
                float obv = __shfl_xor(bv, m);
                int   oix = __shfl_xor(ix, m);
                bool take = (obv < bv) || (obv == bv && oix < ix);
                bv = take ? obv : bv;
                ix = take ? oix : ix;
            }
            int row = quad * 4 + i;                 // wave-local row
            float znr = __shfl(zn, row);            // ||z_row||^2 lives at lane row (l15==row)
            if (l15 == 0) {
                bidxL[wave * 16 + row] = ix;
                lsum += znr + bv;                   // ||z-q||^2 = ||z||^2 + d_best
                atomicAdd(&hist[ix], 1);
            }
        }
        __syncthreads();                            // bidxL visible to all waves

        // epilogue: 64 rows x 64 c. thread: row = lane, c-quarter = wave. coalesced stores.
        {
            int erow = lane;
            int eidx = bidxL[erow];
            int hw = hwb + pass * 64 + erow;
            const unsigned short* qrow = &cbL[eidx * ESTR + wave * 16];
            float* op = ob + (size_t)(wave * 16) * HW + hw;
            #pragma unroll
            for (int cc = 0; cc < 16; ++cc)
                op[(size_t)cc * HW] = bf2f(qrow[cc]);   // err <= 2^-9*|c| ~ 4e-6
        }
        __syncthreads();                            // before next pass rewrites bidxL

        // rotate prefetch
        #pragma unroll
        for (int q2 = 0; q2 < 16; ++q2) zcur[q2] = znxt[q2];
    }

    // loss: owner lanes (l15==0) hold partials; full-wave reduce
    #pragma unroll
    for (int m = 1; m < 64; m <<= 1) lsum += __shfl_xor(lsum, m);
    if (lane == 0) atomicAdd(loss_acc, lsum);

    for (int i = t; i < K_EMB; i += 256) {
        int h = hist[i];
        if (h) atomicAdd(&counts[i], h);
    }
}

__global__ __launch_bounds__(512) void vq_final(const int* __restrict__ counts,
                                                const float* __restrict__ loss_acc,
                                                float* __restrict__ out_scalars) {
    __shared__ float red[512];
    int k = threadIdx.x;
    float pr = (float)counts[k] / (float)NPOS;
    red[k] = pr * logf(pr + 1e-10f);
    __syncthreads();
    for (int s = 256; s > 0; s >>= 1) {
        if (k < s) red[k] += red[k + s];
        __syncthreads();
    }
    if (k == 0) {
        float m = *loss_acc / (float)NELEM;
        out_scalars[0] = m + 0.25f * m;       // vq_loss + 0.25*commitment (identical means)
        out_scalars[1] = expf(-red[0]);       // perplexity
    }
}

extern "C" void kernel_launch(void* const* d_in, const int* in_sizes, int n_in,
                              void* d_out, int out_size, void* d_ws, size_t ws_size,
                              hipStream_t stream) {
    const float* z  = (const float*)d_in[0];
    const float* cb = (const float*)d_in[1];
    float* out = (float*)d_out;

    float* cnorm2        = (float*)d_ws;
    int*   counts        = (int*)((char*)d_ws + 2048);
    float* loss_acc      = (float*)((char*)d_ws + 4096);
    unsigned short* cb16 = (unsigned short*)((char*)d_ws + 8192);   // 64 KB

    vq_prep<<<K_EMB, 64, 0, stream>>>(cb, cnorm2, counts, loss_acc, cb16);
    vq_main<<<512, 256, 0, stream>>>(z, cb16, cnorm2, out, counts, loss_acc);
    vq_final<<<1, 512, 0, stream>>>(counts, loss_acc, out + NELEM);
}

// Round 5
// 124.198 us; speedup vs baseline: 18.7566x; 1.0331x over previous
//
#include <hip/hip_runtime.h>
#include <cfloat>
#include <math.h>

#define K_EMB 512
#define CDIM  64
#define HW    4096        // 64*64 spatial per batch
#define NPOS  131072      // 32*64*64 rows
#define NELEM 8388608     // NPOS*CDIM
#define ESTR  72          // LDS codebook row stride in ushorts (64 data + 8 pad)

typedef __attribute__((ext_vector_type(8))) short short8;
typedef __attribute__((ext_vector_type(4))) float float4v;

// ws layout: [0,2048) float cn1[512]=||c||^2+1 ; [2048,4096) int counts[512] ;
//            [4096,4100) float loss_acc ; [8192,8192+65536) ushort cb16[512*64]

__device__ inline unsigned short f2bf(float f) {          // RTNE fp32->bf16
    unsigned u = __builtin_bit_cast(unsigned, f);
    unsigned r = u + 0x7FFFu + ((u >> 16) & 1u);
    return (unsigned short)(r >> 16);
}
__device__ inline float bf2f(unsigned short h) {
    return __builtin_bit_cast(float, (unsigned)h << 16);
}
__device__ inline unsigned umin2(unsigned a, unsigned b) { return a < b ? a : b; }

// grid 512 x 64: block k -> cn1[k] = ||c_k||^2 + 1, cb16 row k; zero counts/loss
__global__ __launch_bounds__(64) void vq_prep(const float* __restrict__ cb,
                                              float* __restrict__ cn1,
                                              int* __restrict__ counts,
                                              float* __restrict__ loss_acc,
                                              unsigned short* __restrict__ cb16) {
    int k = blockIdx.x, j = threadIdx.x;
    float c = cb[k * CDIM + j];
    float s = c * c;
    #pragma unroll
    for (int m = 1; m < 64; m <<= 1) s += __shfl_xor(s, m);
    cb16[k * CDIM + j] = f2bf(c);
    if (j == 0) {
        cn1[k] = s + 1.0f;
        counts[k] = 0;
        if (k == 0) *loss_acc = 0.f;
    }
}

// 512 blocks x 256 threads; wave handles 64 rows (4 A-tiles), block 256 rows, one pass.
// Per nt (16 entries): 2 ds_read_b128 -> 8 MFMA -> 16x packed argmin (fma+and_or+min_u32).
__global__ __launch_bounds__(256, 2) __attribute__((amdgpu_waves_per_eu(2, 2)))
void vq_main(const float* __restrict__ z,
             const unsigned short* __restrict__ cb16,
             const float* __restrict__ cn1_g,
             float* __restrict__ out,
             int* __restrict__ counts,
             float* __restrict__ loss_acc) {
    __shared__ unsigned short cbL[K_EMB * ESTR];   // 73728 B
    __shared__ float cn1L[K_EMB];                  // 2 KB
    __shared__ int   hist[K_EMB];                  // 2 KB
    __shared__ int   bidxL[256];                   // 1 KB

    int t = threadIdx.x;
    // stage bf16 codebook -> padded LDS
    #pragma unroll
    for (int it = 0; it < 16; ++it) {
        int cid = it * 256 + t;
        int e = cid >> 3, c8 = cid & 7;
        uint4 v = ((const uint4*)cb16)[cid];                 // coalesced 16 B
        *(uint4*)(&cbL[e * ESTR + c8 * 8]) = v;              // ds_write_b128
    }
    for (int i = t; i < K_EMB; i += 256) { cn1L[i] = cn1_g[i]; hist[i] = 0; }

    int lane = t & 63, wave = t >> 6;
    int l15 = lane & 15, quad = lane >> 4;
    int p0  = blockIdx.x * 256;            // 256 consecutive rows; one batch (256|4096)
    int b   = p0 >> 12;
    int hwb = p0 & 4095;
    const float* zb = z + (size_t)b * (CDIM * HW);
    float* ob = out + (size_t)b * (CDIM * HW);

    // load z for 4 row-tiles, build bf16 A-frags, accumulate sum(z^2)
    // A layout: A[m=l15][k=quad*8+j], c = kt*32 + quad*8 + j
    short8 afrag[4][2];
    float zsq = 0.f;
    int hw0 = hwb + wave * 64 + l15;
    #pragma unroll
    for (int r = 0; r < 4; ++r)
        #pragma unroll
        for (int kt = 0; kt < 2; ++kt)
            #pragma unroll
            for (int j = 0; j < 8; ++j) {
                float f = zb[(size_t)(kt * 32 + quad * 8 + j) * HW + hw0 + r * 16];
                zsq = fmaf(f, f, zsq);
                afrag[r][kt][j] = (short)f2bf(f);
            }
    __syncthreads();

    // n-loop: 32 tiles of 16 entries. key = cn1 - 2 z.c  in (0.5, 1.5) -> bits monotone.
    unsigned umin[4][4];
    #pragma unroll
    for (int r = 0; r < 4; ++r)
        #pragma unroll
        for (int i = 0; i < 4; ++i) umin[r][i] = 0xFFFFFFFFu;

    const unsigned short* bbase = &cbL[l15 * ESTR + quad * 8];
    #pragma unroll 4
    for (int nt = 0; nt < 32; ++nt) {
        short8 b0 = *(const short8*)(bbase);          // B[n=l15][k=quad*8+j], c 0..31
        short8 b1 = *(const short8*)(bbase + 32);     // c 32..63
        bbase += 16 * ESTR;
        float cn1 = cn1L[nt * 16 + l15];
        unsigned e = (unsigned)(nt * 16 + l15);
        float4v acc[4];
        #pragma unroll
        for (int r = 0; r < 4; ++r) {
            float4v zz = {0.f, 0.f, 0.f, 0.f};
            zz = __builtin_amdgcn_mfma_f32_16x16x32_bf16(afrag[r][0], b0, zz, 0, 0, 0);
            acc[r] = __builtin_amdgcn_mfma_f32_16x16x32_bf16(afrag[r][1], b1, zz, 0, 0, 0);
        }
        #pragma unroll
        for (int r = 0; r < 4; ++r)
            #pragma unroll
            for (int i = 0; i < 4; ++i) {
                float key = fmaf(-2.f, acc[r][i], cn1);
                unsigned u = (__builtin_bit_cast(unsigned, key) & 0xFFFFFE00u) | e;
                umin[r][i] = umin2(umin[r][i], u);
            }
    }

    // reduce across the 16 entry-lanes of each quad; row = quad*4 + i (C/D layout)
    float lsum = zsq;
    #pragma unroll
    for (int r = 0; r < 4; ++r)
        #pragma unroll
        for (int i = 0; i < 4; ++i) {
            unsigned u = umin[r][i];
            u = umin2(u, (unsigned)__shfl_xor((int)u, 1));
            u = umin2(u, (unsigned)__shfl_xor((int)u, 2));
            u = umin2(u, (unsigned)__shfl_xor((int)u, 4));
            u = umin2(u, (unsigned)__shfl_xor((int)u, 8));
            if (l15 == 0) {
                int idx = (int)(u & 511u);
                float d = __builtin_bit_cast(float, u & 0xFFFFFE00u) - 1.0f;
                lsum += d;                             // ||z-q||^2 = z^2-part + d
                bidxL[wave * 64 + r * 16 + quad * 4 + i] = idx;
                atomicAdd(&hist[idx], 1);
            }
        }
    #pragma unroll
    for (int m = 1; m < 64; m <<= 1) lsum += __shfl_xor(lsum, m);
    if (lane == 0) atomicAdd(loss_acc, lsum);
    __syncthreads();                                   // bidxL + hist complete

    // epilogue: thread t -> row t; 8x ds_read_b128, 64 coalesced dword stores
    {
        int eidx = bidxL[t];
        const unsigned short* qrow = &cbL[eidx * ESTR];
        float* op = ob + hwb + t;
        #pragma unroll
        for (int c8 = 0; c8 < 8; ++c8) {
            short8 qv = *(const short8*)(qrow + c8 * 8);
            #pragma unroll
            for (int j = 0; j < 8; ++j)
                op[(size_t)(c8 * 8 + j) * HW] = bf2f((unsigned short)qv[j]);
        }
    }
    for (int i = t; i < K_EMB; i += 256) {
        int h = hist[i];
        if (h) atomicAdd(&counts[i], h);
    }
}

__global__ __launch_bounds__(512) void vq_final(const int* __restrict__ counts,
                                                const float* __restrict__ loss_acc,
                                                float* __restrict__ out_scalars) {
    __shared__ float red[512];
    int k = threadIdx.x;
    float pr = (float)counts[k] / (float)NPOS;
    red[k] = pr * logf(pr + 1e-10f);
    __syncthreads();
    for (int s = 256; s > 0; s >>= 1) {
        if (k < s) red[k] += red[k + s];
        __syncthreads();
    }
    if (k == 0) {
        float m = *loss_acc / (float)NELEM;
        out_scalars[0] = m + 0.25f * m;       // vq_loss + 0.25*commitment (identical means)
        out_scalars[1] = expf(-red[0]);       // perplexity
    }
}

extern "C" void kernel_launch(void* const* d_in, const int* in_sizes, int n_in,
                              void* d_out, int out_size, void* d_ws, size_t ws_size,
                              hipStream_t stream) {
    const float* z  = (const float*)d_in[0];
    const float* cb = (const float*)d_in[1];
    float* out = (float*)d_out;

    float* cn1           = (float*)d_ws;
    int*   counts        = (int*)((char*)d_ws + 2048);
    float* loss_acc      = (float*)((char*)d_ws + 4096);
    unsigned short* cb16 = (unsigned short*)((char*)d_ws + 8192);   // 64 KB

    vq_prep<<<K_EMB, 64, 0, stream>>>(cb, cn1, counts, loss_acc, cb16);
    vq_main<<<512, 256, 0, stream>>>(z, cb16, cn1, out, counts, loss_acc);
    vq_final<<<1, 512, 0, stream>>>(counts, loss_acc, out + NELEM);
}

// Round 6
// 120.160 us; speedup vs baseline: 19.3869x; 1.0336x over previous
//
#include <hip/hip_runtime.h>
#include <cfloat>
#include <math.h>

#define K_EMB 512
#define CDIM  64
#define HW    4096        // 64*64 spatial per batch
#define NPOS  131072      // 32*64*64 rows
#define NELEM 8388608     // NPOS*CDIM
#define RPB   128         // rows per block
#define NBLK  (NPOS / RPB)   // 1024 blocks

typedef __attribute__((ext_vector_type(8))) short short8;
typedef __attribute__((ext_vector_type(4))) float float4v;

// ws layout: [0,2048) float cn1[512]=||c||^2+1 ; [2048,4096) int counts[512] ;
//            [4096,8192) float lossArr[1024] ; [8192,73728) ushort cb16[512*64]

__device__ inline unsigned short f2bf(float f) {          // RTNE fp32->bf16
    unsigned u = __builtin_bit_cast(unsigned, f);
    unsigned r = u + 0x7FFFu + ((u >> 16) & 1u);
    return (unsigned short)(r >> 16);
}
__device__ inline unsigned umin2(unsigned a, unsigned b) { return a < b ? a : b; }

__global__ __launch_bounds__(64) void vq_prep(const float* __restrict__ cb,
                                              float* __restrict__ cn1,
                                              int* __restrict__ counts,
                                              unsigned short* __restrict__ cb16) {
    int k = blockIdx.x, j = threadIdx.x;
    float c = cb[k * CDIM + j];
    float s = c * c;
    #pragma unroll
    for (int m = 1; m < 64; m <<= 1) s += __shfl_xor(s, m);
    cb16[k * CDIM + j] = f2bf(c);
    if (j == 0) {
        cn1[k] = s + 1.0f;
        counts[k] = 0;
    }
}

// 1024 blocks x 256 thr (4 waves). Wave w holds entries [w*128,(w+1)*128) as
// B-frags in 64 VGPRs (no LDS codebook). z tile transposed into 32KB LDS fp32.
// Argmin k-split across waves, merged via 2KB LDS. Loss exact (fp32 gather),
// no loss atomics; counts flush line-rotated per block.
__global__ __launch_bounds__(256) __attribute__((amdgpu_waves_per_eu(4, 4)))
void vq_main(const float* __restrict__ z,
             const unsigned short* __restrict__ cb16,
             const float* __restrict__ cbf,
             const float* __restrict__ cn1_g,
             float* __restrict__ out,
             int* __restrict__ counts,
             float* __restrict__ lossArr) {
    __shared__ float   zL[RPB * CDIM];     // 32 KB, XOR-swizzled 16B groups
    __shared__ unsigned mergeL[RPB * 4];   // 2 KB: [row][wave] packed best
    __shared__ int     hist[K_EMB];        // 2 KB
    __shared__ float   lossW[4];

    int t = threadIdx.x;
    int lane = t & 63, w = t >> 6;
    int l15 = lane & 15, quad = lane >> 4;

    int p0  = blockIdx.x * RPB;            // 128 | 4096 -> single batch per block
    int b   = p0 >> 12;
    int hwb = p0 & 4095;
    const float* zb = z + (size_t)b * (CDIM * HW);
    float* ob = out + (size_t)b * (CDIM * HW);

    // B-frags: wave w's 128 entries -> 64 VGPRs. B[n=l15][k=quad*8+j], c=kt*32+quad*8+j
    short8 bfr[8][2];
    float  cn1r[8];
    #pragma unroll
    for (int nt = 0; nt < 8; ++nt) {
        int e = w * 128 + nt * 16 + l15;
        #pragma unroll
        for (int kt = 0; kt < 2; ++kt)
            bfr[nt][kt] = *(const short8*)(cb16 + e * CDIM + kt * 32 + quad * 8);
        cn1r[nt] = cn1_g[e];
    }
    for (int i = t; i < K_EMB; i += 256) hist[i] = 0;

    // stage z tile: coalesced float4 along hw, transposed scatter into zL.
    // zL[r][c] at dword r*64 + ((c>>2) ^ (r&15))*4 + (c&3)
    #pragma unroll
    for (int i = 0; i < 8; ++i) {
        int fi  = i * 256 + t;
        int c0  = fi >> 5;                 // 32 float4 per c-row
        int hw4 = fi & 31;
        float4 v = *(const float4*)(zb + (size_t)c0 * HW + hwb + hw4 * 4);
        int slot = ((c0 >> 2) ^ ((hw4 * 4) & 15)) * 4 + (c0 & 3);   // r&15 == (hw4*4+u)&15
        zL[(hw4 * 4 + 0) * 64 + (((c0 >> 2) ^ ((hw4 * 4 + 0) & 15)) * 4 + (c0 & 3))] = v.x;
        zL[(hw4 * 4 + 1) * 64 + (((c0 >> 2) ^ ((hw4 * 4 + 1) & 15)) * 4 + (c0 & 3))] = v.y;
        zL[(hw4 * 4 + 2) * 64 + (((c0 >> 2) ^ ((hw4 * 4 + 2) & 15)) * 4 + (c0 & 3))] = v.z;
        zL[(hw4 * 4 + 3) * 64 + (((c0 >> 2) ^ ((hw4 * 4 + 3) & 15)) * 4 + (c0 & 3))] = v.w;
        (void)slot;
    }
    __syncthreads();

    // n-loop: 8 row-tiles x (wave's 8 entry-tiles). key = cn1 - 2 z.c, packed argmin.
    unsigned ebase = (unsigned)(w * 128 + l15);
    #pragma unroll
    for (int T = 0; T < 8; ++T) {
        int r = T * 16 + l15;
        short8 a0, a1;
        #pragma unroll
        for (int kt = 0; kt < 2; ++kt) {
            int g0 = kt * 8 + quad * 2;
            float4 f0 = *(const float4*)&zL[r * 64 + ((g0 ^ l15) * 4)];
            float4 f1 = *(const float4*)&zL[r * 64 + (((g0 + 1) ^ l15) * 4)];
            short8& a = kt ? a1 : a0;
            a[0] = (short)f2bf(f0.x); a[1] = (short)f2bf(f0.y);
            a[2] = (short)f2bf(f0.z); a[3] = (short)f2bf(f0.w);
            a[4] = (short)f2bf(f1.x); a[5] = (short)f2bf(f1.y);
            a[6] = (short)f2bf(f1.z); a[7] = (short)f2bf(f1.w);
        }
        unsigned umin[4] = {0xFFFFFFFFu, 0xFFFFFFFFu, 0xFFFFFFFFu, 0xFFFFFFFFu};
        #pragma unroll
        for (int nt = 0; nt < 8; ++nt) {
            float4v acc = {0.f, 0.f, 0.f, 0.f};
            acc = __builtin_amdgcn_mfma_f32_16x16x32_bf16(a0, bfr[nt][0], acc, 0, 0, 0);
            acc = __builtin_amdgcn_mfma_f32_16x16x32_bf16(a1, bfr[nt][1], acc, 0, 0, 0);
            unsigned e = ebase + nt * 16;
            #pragma unroll
            for (int i = 0; i < 4; ++i) {
                float key = fmaf(-2.f, acc[i], cn1r[nt]);     // in (0.5,1.5): bits monotone
                unsigned u = (__builtin_bit_cast(unsigned, key) & 0xFFFFFE00u) | e;
                umin[i] = umin2(umin[i], u);
            }
        }
        #pragma unroll
        for (int i = 0; i < 4; ++i) {                          // reduce over 16 entry-lanes
            unsigned u = umin[i];
            u = umin2(u, (unsigned)__shfl_xor((int)u, 1));
            u = umin2(u, (unsigned)__shfl_xor((int)u, 2));
            u = umin2(u, (unsigned)__shfl_xor((int)u, 4));
            u = umin2(u, (unsigned)__shfl_xor((int)u, 8));
            if (l15 == 0) mergeL[(T * 16 + quad * 4 + i) * 4 + w] = u;  // row=quad*4+i
        }
    }
    __syncthreads();

    // epilogue: thread pair per row. rr = t>>1, half h = t&1 (32 c each).
    int rr = t >> 1, h = t & 1;
    uint4 m4 = *(const uint4*)&mergeL[rr * 4];
    unsigned u = umin2(umin2(m4.x, m4.y), umin2(m4.z, m4.w));
    int idx = (int)(u & 511u);
    if (h == 0) atomicAdd(&hist[idx], 1);

    float lsum = 0.f;
    {
        const float* q = cbf + idx * CDIM + h * 32;            // exact fp32 codebook
        float* op = ob + hwb + rr;
        #pragma unroll
        for (int g = 0; g < 8; ++g) {
            int gg = h * 8 + g;                                // c group
            float4 zv = *(const float4*)&zL[rr * 64 + ((gg ^ (rr & 15)) * 4)];
            float4 qv = *(const float4*)(q + g * 4);
            float d0 = qv.x - zv.x, d1 = qv.y - zv.y, d2 = qv.z - zv.z, d3 = qv.w - zv.w;
            int c = h * 32 + g * 4;
            op[(size_t)(c + 0) * HW] = zv.x + d0;              // reference rounding z+(q-z)
            op[(size_t)(c + 1) * HW] = zv.y + d1;
            op[(size_t)(c + 2) * HW] = zv.z + d2;
            op[(size_t)(c + 3) * HW] = zv.w + d3;
            lsum = fmaf(d0, d0, lsum); lsum = fmaf(d1, d1, lsum);
            lsum = fmaf(d2, d2, lsum); lsum = fmaf(d3, d3, lsum);
        }
    }
    #pragma unroll
    for (int m = 1; m < 64; m <<= 1) lsum += __shfl_xor(lsum, m);
    if (lane == 0) lossW[w] = lsum;
    __syncthreads();                                           // hist + lossW complete

    if (t == 0) lossArr[blockIdx.x] = lossW[0] + lossW[1] + lossW[2] + lossW[3];

    // counts flush, start line rotated per block (avoid lockstep line-0 storm)
    int rot = (blockIdx.x * 16) & 511;
    for (int i = t; i < K_EMB; i += 256) {
        int k = (i + rot) & 511;
        int hv = hist[k];
        if (hv) atomicAdd(&counts[k], hv);
    }
}

__global__ __launch_bounds__(512) void vq_final(const int* __restrict__ counts,
                                                const float* __restrict__ lossArr,
                                                float* __restrict__ out_scalars) {
    __shared__ float re[512];
    __shared__ float rl[512];
    int k = threadIdx.x;
    float pr = (float)counts[k] / (float)NPOS;
    re[k] = pr * logf(pr + 1e-10f);
    rl[k] = lossArr[k] + lossArr[k + 512];
    __syncthreads();
    for (int s = 256; s > 0; s >>= 1) {
        if (k < s) { re[k] += re[k + s]; rl[k] += rl[k + s]; }
        __syncthreads();
    }
    if (k == 0) {
        float m = rl[0] / (float)NELEM;
        out_scalars[0] = 1.25f * m;           // vq_loss + 0.25*commitment (identical means)
        out_scalars[1] = expf(-re[0]);        // perplexity
    }
}

extern "C" void kernel_launch(void* const* d_in, const int* in_sizes, int n_in,
                              void* d_out, int out_size, void* d_ws, size_t ws_size,
                              hipStream_t stream) {
    const float* z  = (const float*)d_in[0];
    const float* cb = (const float*)d_in[1];
    float* out = (float*)d_out;

    float* cn1           = (float*)d_ws;
    int*   counts        = (int*)((char*)d_ws + 2048);
    float* lossArr       = (float*)((char*)d_ws + 4096);
    unsigned short* cb16 = (unsigned short*)((char*)d_ws + 8192);   // 64 KB

    vq_prep<<<K_EMB, 64, 0, stream>>>(cb, cn1, counts, cb16);
    vq_main<<<NBLK, 256, 0, stream>>>(z, cb16, cb, cn1, out, counts, lossArr);
    vq_final<<<1, 512, 0, stream>>>(counts, lossArr, out + NELEM);
}